// Round 8
// baseline (1033.422 us; speedup 1.0000x reference)
//
#include <hip/hip_runtime.h>
#include <cstdint>
#include <cmath>

// ---------------- constants ----------------
namespace {
constexpr int BATCH = 4;
constexpr int CIN   = 512;
constexpr int CMID  = 512;
constexpr int HSZ   = 64, WSZ = 64, HWP = 4096;
constexpr int NA    = 36864;          // HW * 9 anchors
constexpr int NIN_  = 6000;
constexpr int NOUT2 = 300;
constexpr int NW    = 94;             // ceil(6000/64) u64 words per bitmask row

// d_out layout (float offsets)
constexpr size_t O_SC  = 0;           // rpn_scores (4,36864,2)
constexpr size_t O_LC  = 294912;      // rpn_locs   (4,36864,4)
constexpr size_t O_ROI = 884736;      // rois       (1200,4)
constexpr size_t O_IDX = 889536;      // roi_indices(1200)
constexpr size_t O_ANC = 890736;      // anchors    (36864,4)

// d_ws layout (float offsets). Phase A: h + w-split. Phase B (post-K2) aliases h.
// High-water = 10747904 floats = 43.0 MB (same as the proven R1-R7 layout).
constexpr size_t W_H    = 0;          // 8388608 floats (conv hidden, NCHW)
constexpr size_t W_WHI  = 8388608;    // 2359296 f16 W hi, [kk][co][ci]
constexpr size_t W_WLO  = 9568256;    // 2359296 f16 W lo (scaled 2048)
constexpr size_t W_R4   = 0;          // 589824  rois per anchor (aliases h)
constexpr size_t W_SK   = 589824;     // 147456  score keys (fg or -inf)
constexpr size_t W_CNT  = 753664;     // 4 ints   compact counter
constexpr size_t W_CUT  = 753668;     // 4 ints   cut1
constexpr size_t W_CUT2 = 753676;     // 4 ints
constexpr size_t W_CUT3 = 753684;     // 4 ints   (region W_CNT..753695 memset to 0)
constexpr size_t W_CKEY = 901184;     // 147456 u64 keys (8B aligned)
constexpr size_t W_RS   = 1196096;    // 96000  sorted rois (4,6000,4)
constexpr size_t W_VS   = 1292096;    // 24000 ints sorted validity
constexpr size_t W_MAT  = 1316096;    // 4*6000*94 u64 (suppression bits)
} // namespace

typedef _Float16 f16;
typedef __attribute__((ext_vector_type(4))) _Float16 f16x4;
typedef __attribute__((ext_vector_type(8))) _Float16 f16x8;
typedef __attribute__((ext_vector_type(4))) float f32x4;

// ---------------- K0w: split conv_w*64 into f16 hi/lo, layout [kk][co][ci] ----------------
__global__ __launch_bounds__(256) void k0w(const float* __restrict__ w,
                                           f16* __restrict__ whi, f16* __restrict__ wlo) {
    int o = blockIdx.x * 256 + threadIdx.x;     // 2359296 total
    int ci = o & 511;
    int r  = o >> 9;
    int co = r & 511;
    int kk = r >> 9;
    float f = w[(co * CIN + ci) * 9 + kk] * 64.0f;   // scale 64: keep hi out of f16-subnormals
    f16 hv = (f16)f;
    whi[o] = hv;
    wlo[o] = (f16)((f - (float)hv) * 2048.0f);       // lo scaled 2^11 into normal range
}

// ---------------- K1: 3x3 conv + bias + ReLU via f16-split MFMA (3 products) ----------
// chunk-outer (16) x fully-unrolled 9-shift inner: compile-time ky/kx -> immediate
// LDS offsets; W tile XOR-swizzled (ci ^ ((co>>1)&3)<<3) to break the 8-way bank
// conflict of the 16-dword ci stride (X's x40 stride is already 2-way/free).
// Same MFMA sequence as R7 -> bit-identical h.
__global__ __launch_bounds__(256, 2) void k1_mfma(const float* __restrict__ x,
                                                  const f16* __restrict__ gwh,
                                                  const f16* __restrict__ gwl,
                                                  const float* __restrict__ bias,
                                                  float* __restrict__ h) {
    const int pt = blockIdx.x, cg = blockIdx.y, b = blockIdx.z;
    const int y0 = pt * 2, co0 = cg * 128;
    const int t = threadIdx.x;
    const int wave = t >> 6, lane = t & 63;
    const int wrow = wave >> 1, wco = wave & 1;
    const int m = lane & 15, q = lane >> 4;

    // X tile: [hi/lo][(row*66 + col)*40 + ci]  rows y0-1..y0+2, col = img_x+1, ci 0..31 (pad 40)
    __shared__ __align__(16) f16 xs[2][4 * 66 * 40];
    // W tile: [slot][hi/lo][co*32 + (ci ^ swz(co))]
    __shared__ __align__(16) f16 wt[2][2][128 * 32];

    f32x4 acc1[4][4], acc2[4][4];
#pragma unroll
    for (int i = 0; i < 4; ++i)
#pragma unroll
        for (int j = 0; j < 4; ++j) { acc1[i][j] = (f32x4)0.0f; acc2[i][j] = (f32x4)0.0f; }

    // X staging roles
    const int cq = t & 7, srow = (t >> 3) & 3, cseg = t >> 5;
    const int gy = y0 - 1 + srow;
    const bool yok = (gy >= 0 && gy < HSZ);

    // zero the padding columns (img_x=-1 -> col 0, img_x=64 -> col 65); never rewritten
    if (t < 128) {
        int buf = t >> 6, rr = (t >> 4) & 3, cc = ((t >> 3) & 1) ? 65 : 0, cq2 = t & 7;
        f16x4 z = (f16x4)(f16)0.0f;
        *(f16x4*)&xs[buf][(rr * 66 + cc) * 40 + cq2 * 4] = z;
    }

    // W staging thread constants (2 strided slots of 256 cover 512 f16x8 tasks)
    int wbase[2], wpos[2];
#pragma unroll
    for (int s = 0; s < 2; ++s) {
        int idx = s * 256 + t;
        int co_l = idx >> 2, q8 = idx & 3;
        wbase[s] = (co0 + co_l) * 512 + q8 * 8;                       // gw offset for (kk=0,chunk=0)
        wpos[s]  = co_l * 32 + ((q8 * 8) ^ (((co_l >> 1) & 3) << 3)); // swizzled LDS pos
    }

    // prologue: stage W(kk=0, chunk=0) into slot 0
#pragma unroll
    for (int s = 0; s < 2; ++s) {
        *(f16x8*)&wt[0][0][wpos[s]] = *(const f16x8*)&gwh[wbase[s]];
        *(f16x8*)&wt[0][1][wpos[s]] = *(const f16x8*)&gwl[wbase[s]];
    }

    // hoisted read bases
    const int swzB  = ((m >> 1) & 3) << 3;
    const int baseB = wco * 2048 + m * 32 + ((q * 8) ^ swzB);   // within a wt plane (4096 f16)
    const int baseA = wrow * 2640 + m * 40 + q * 8;             // within an xs plane (10560 f16)

    for (int chunk = 0; chunk < 16; ++chunk) {
        const int slot0 = chunk & 1;
        __syncthreads();   // prev chunk's kk=8 compute done -> xs and wt[slot0^1] free

        // stage X(chunk): thread = (cq, srow, cseg); 4 ci x 8 cols, split to f16 hi/lo
        {
            float vb[4][8];
            const float* xp = x + ((size_t)(b * CIN + chunk * 32 + cq * 4)) * HWP + gy * WSZ + cseg * 8;
#pragma unroll
            for (int i = 0; i < 4; ++i) {
                if (yok) {
                    float4 u0 = *(const float4*)(xp + (size_t)i * HWP);
                    float4 u1 = *(const float4*)(xp + (size_t)i * HWP + 4);
                    vb[i][0] = u0.x; vb[i][1] = u0.y; vb[i][2] = u0.z; vb[i][3] = u0.w;
                    vb[i][4] = u1.x; vb[i][5] = u1.y; vb[i][6] = u1.z; vb[i][7] = u1.w;
                } else {
#pragma unroll
                    for (int jj = 0; jj < 8; ++jj) vb[i][jj] = 0.0f;
                }
            }
#pragma unroll
            for (int j = 0; j < 8; ++j) {
                int c = (j + cq) & 7;            // k-rotation: spread LDS banks across lanes
                int col = cseg * 8 + c + 1;
                f16x4 hv, lv;
#pragma unroll
                for (int i = 0; i < 4; ++i) {
                    float f = vb[i][c];
                    f16 hf = (f16)f;
                    hv[i] = hf;
                    lv[i] = (f16)((f - (float)hf) * 2048.0f);
                }
                int base = (srow * 66 + col) * 40 + cq * 4;
                *(f16x4*)&xs[0][base] = hv;
                *(f16x4*)&xs[1][base] = lv;
            }
        }
        // prefetch W(kk=1, chunk) into wt[slot0^1]
#pragma unroll
        for (int s = 0; s < 2; ++s) {
            int g = wbase[s] + 262144 + chunk * 32;
            *(f16x8*)&wt[slot0 ^ 1][0][wpos[s]] = *(const f16x8*)&gwh[g];
            *(f16x8*)&wt[slot0 ^ 1][1][wpos[s]] = *(const f16x8*)&gwl[g];
        }
        __syncthreads();   // X(chunk) ready (W(kk=0) ready since previous section)

#pragma unroll
        for (int kk = 0; kk < 9; ++kk) {
            const int slot = (chunk + kk) & 1;     // parity(chunk*9+kk), 9 odd
            if (kk > 0) {
                __syncthreads();                   // prev section's wt[slot^1] reads done
                if (kk < 8) {
#pragma unroll
                    for (int s = 0; s < 2; ++s) {
                        int g = wbase[s] + (kk + 1) * 262144 + chunk * 32;
                        *(f16x8*)&wt[slot ^ 1][0][wpos[s]] = *(const f16x8*)&gwh[g];
                        *(f16x8*)&wt[slot ^ 1][1][wpos[s]] = *(const f16x8*)&gwl[g];
                    }
                } else if (chunk < 15) {           // wrap: (kk=0, chunk+1)
#pragma unroll
                    for (int s = 0; s < 2; ++s) {
                        int g = wbase[s] + (chunk + 1) * 32;
                        *(f16x8*)&wt[slot ^ 1][0][wpos[s]] = *(const f16x8*)&gwh[g];
                        *(f16x8*)&wt[slot ^ 1][1][wpos[s]] = *(const f16x8*)&gwl[g];
                    }
                }
            }
            const int ky = kk / 3, kx = kk - ky * 3;   // compile-time after unroll

            f16x8 bh[4], bl[4], ah[4], al[4];
#pragma unroll
            for (int nt = 0; nt < 4; ++nt) {
                int off = baseB + nt * 512;
                bh[nt] = *(const f16x8*)&wt[slot][0][off];
                bl[nt] = *(const f16x8*)&wt[slot][1][off];
            }
#pragma unroll
            for (int ct = 0; ct < 4; ++ct) {
                int off = baseA + ky * 2640 + kx * 40 + ct * 640;
                ah[ct] = *(const f16x8*)&xs[0][off];
                al[ct] = *(const f16x8*)&xs[1][off];
            }
#pragma unroll
            for (int ct = 0; ct < 4; ++ct)
#pragma unroll
                for (int nt = 0; nt < 4; ++nt) {
                    acc1[ct][nt] = __builtin_amdgcn_mfma_f32_16x16x32_f16(ah[ct], bh[nt], acc1[ct][nt], 0, 0, 0);
                    acc2[ct][nt] = __builtin_amdgcn_mfma_f32_16x16x32_f16(ah[ct], bl[nt], acc2[ct][nt], 0, 0, 0);
                    acc2[ct][nt] = __builtin_amdgcn_mfma_f32_16x16x32_f16(al[ct], bh[nt], acc2[ct][nt], 0, 0, 0);
                }
        }
    }

    // epilogue: h = (acc1 + acc2*2^-11)*2^-6 + bias, relu
    const int y = y0 + wrow;
#pragma unroll
    for (int nt = 0; nt < 4; ++nt) {
        const int co = co0 + wco * 64 + nt * 16 + m;    // D: n = lane&15
        const float bv = bias[co];
        size_t rowbase = ((size_t)(b * CMID + co)) * HWP + y * WSZ;
#pragma unroll
        for (int ct = 0; ct < 4; ++ct) {
            float4 o;
            o.x = fmaxf((acc1[ct][nt][0] + acc2[ct][nt][0] * (1.0f / 2048.0f)) * (1.0f / 64.0f) + bv, 0.0f);
            o.y = fmaxf((acc1[ct][nt][1] + acc2[ct][nt][1] * (1.0f / 2048.0f)) * (1.0f / 64.0f) + bv, 0.0f);
            o.z = fmaxf((acc1[ct][nt][2] + acc2[ct][nt][2] * (1.0f / 2048.0f)) * (1.0f / 64.0f) + bv, 0.0f);
            o.w = fmaxf((acc1[ct][nt][3] + acc2[ct][nt][3] * (1.0f / 2048.0f)) * (1.0f / 64.0f) + bv, 0.0f);
            *(float4*)&h[rowbase + ct * 16 + q * 4] = o;   // D: m = q*4+reg -> img x
        }
    }
}

// ---------------- K2: 1x1 convs (score 18 + loc 36) -> d_out in NHWC-anchor layout ----------
__global__ __launch_bounds__(256) void k2_conv1(const float* __restrict__ h,
                                                const float* __restrict__ sw,
                                                const float* __restrict__ sb,
                                                const float* __restrict__ lw,
                                                const float* __restrict__ lb,
                                                float* __restrict__ out) {
    const int y = blockIdx.x;
    const int b = blockIdx.y;
    const int t = threadIdx.x;
    const int c4  = (t & 15) * 4;
    const int px4 = (t >> 4) * 4;
    __shared__ __align__(16) float hs[1024];        // [ci(16)][px(64)]
    __shared__ __align__(16) float wsm[16 * 68];    // [ci][c] padded

    float acc[4][4];
#pragma unroll
    for (int i = 0; i < 4; ++i)
#pragma unroll
        for (int j = 0; j < 4; ++j) acc[i][j] = 0.f;

    const int s_px = (t & 15) * 4;
    const int s_ci = t >> 4;
    for (int ci0 = 0; ci0 < CMID; ci0 += 16) {
        *(float4*)&hs[s_ci * 64 + s_px] =
            *(const float4*)&h[((size_t)(b * CMID + ci0 + s_ci)) * HWP + y * 64 + s_px];
#pragma unroll
        for (int k = 0; k < 4; ++k) {
            int idx = k * 256 + t;
            int ci = idx & 15, c = idx >> 4;
            float v = 0.f;
            if (c < 18) v = sw[c * 512 + ci0 + ci];
            else if (c < 54) v = lw[(c - 18) * 512 + ci0 + ci];
            wsm[ci * 68 + c] = v;
        }
        __syncthreads();
#pragma unroll
        for (int ci = 0; ci < 16; ++ci) {
            float4 hv = *(const float4*)&hs[ci * 64 + px4];
            float4 wv = *(const float4*)&wsm[ci * 68 + c4];
            acc[0][0] = fmaf(wv.x, hv.x, acc[0][0]);
            acc[0][1] = fmaf(wv.x, hv.y, acc[0][1]);
            acc[0][2] = fmaf(wv.x, hv.z, acc[0][2]);
            acc[0][3] = fmaf(wv.x, hv.w, acc[0][3]);
            acc[1][0] = fmaf(wv.y, hv.x, acc[1][0]);
            acc[1][1] = fmaf(wv.y, hv.y, acc[1][1]);
            acc[1][2] = fmaf(wv.y, hv.z, acc[1][2]);
            acc[1][3] = fmaf(wv.y, hv.w, acc[1][3]);
            acc[2][0] = fmaf(wv.z, hv.x, acc[2][0]);
            acc[2][1] = fmaf(wv.z, hv.y, acc[2][1]);
            acc[2][2] = fmaf(wv.z, hv.z, acc[2][2]);
            acc[2][3] = fmaf(wv.z, hv.w, acc[2][3]);
            acc[3][0] = fmaf(wv.w, hv.x, acc[3][0]);
            acc[3][1] = fmaf(wv.w, hv.y, acc[3][1]);
            acc[3][2] = fmaf(wv.w, hv.z, acc[3][2]);
            acc[3][3] = fmaf(wv.w, hv.w, acc[3][3]);
        }
        __syncthreads();
    }

#pragma unroll
    for (int cc = 0; cc < 4; ++cc) {
        int c = c4 + cc;
        if (c >= 54) break;
        float bv = (c < 18) ? sb[c] : lb[c - 18];
#pragma unroll
        for (int pp = 0; pp < 4; ++pp) {
            int px = y * 64 + px4 + pp;
            float v = acc[cc][pp] + bv;
            if (c < 18)
                out[O_SC + (size_t)b * 73728 + (size_t)px * 18 + c] = v;
            else
                out[O_LC + (size_t)b * 147456 + (size_t)px * 36 + (c - 18)] = v;
        }
    }
}

// ---------------- K3: anchors + softmax-fg + loc2bbox + clip (no histogram) ----------
__global__ __launch_bounds__(256) void k3_prop(float* __restrict__ out,
                                               float* __restrict__ rois4,
                                               float* __restrict__ skey) {
    const int t = threadIdx.x;
    const int p = blockIdx.x * 256 + t;
    const int b = blockIdx.y;
    const int px = p / 9;
    const int a  = p - px * 9;
    const int yy = px >> 6, xx = px & 63;
    const int ri = a / 3, si = a - ri * 3;
    const double rat[3] = {0.5, 1.0, 2.0};
    const double scl[3] = {8.0, 16.0, 32.0};
    double hhd = 16.0 * scl[si] * sqrt(rat[ri]);
    double wwd = 16.0 * scl[si] * sqrt(1.0 / rat[ri]);
    float a0 = (float)(8.0 - hhd / 2.0), a1 = (float)(8.0 - wwd / 2.0);
    float a2 = (float)(8.0 + hhd / 2.0), a3 = (float)(8.0 + wwd / 2.0);
    float sy = (float)(yy * 16), sx = (float)(xx * 16);
    float A0 = sy + a0, A1 = sx + a1, A2 = sy + a2, A3 = sx + a3;
    if (b == 0) {
        float4 av; av.x = A0; av.y = A1; av.z = A2; av.w = A3;
        *(float4*)&out[O_ANC + (size_t)p * 4] = av;
    }
    const float* sc = out + O_SC + (size_t)b * 73728 + (size_t)px * 18 + a * 2;
    float s0 = sc[0], s1 = sc[1];
    float mm = fmaxf(s0, s1);
    float e0 = expf(s0 - mm), e1 = expf(s1 - mm);
    float fg = e1 / (e0 + e1);
    const float* lc = out + O_LC + (size_t)b * 147456 + (size_t)px * 36 + a * 4;
    float dy = lc[0], dxv = lc[1], dh = lc[2], dwv = lc[3];
    float ah = A2 - A0, aw = A3 - A1;
    float cy = A0 + 0.5f * ah, cx = A1 + 0.5f * aw;
    float cty = dy * ah + cy, ctx = dxv * aw + cx;
    float th = expf(dh) * ah, tw = expf(dwv) * aw;
    float ry1 = cty - 0.5f * th, rx1 = ctx - 0.5f * tw;
    float ry2 = cty + 0.5f * th, rx2 = ctx + 0.5f * tw;
    float y1 = fminf(fmaxf(ry1, 0.f), 1024.f);
    float y2 = fminf(fmaxf(ry2, 0.f), 1024.f);
    float x1 = fminf(fmaxf(rx1, 0.f), 1024.f);
    float x2 = fminf(fmaxf(rx2, 0.f), 1024.f);
    bool valid = ((y2 - y1) >= 16.f) && ((x2 - x1) >= 16.f);
    float sk = valid ? fg : -__builtin_inff();
    float4 rv; rv.x = y1; rv.y = x1; rv.z = y2; rv.w = x2;
    *(float4*)&rois4[((size_t)b * NA + p) * 4] = rv;
    skey[(size_t)b * NA + p] = sk;
}

// ---------------- K4r: 3-level radix cut in one kernel (1 block/batch, 1024 thr) -------
// Level digits: (u>>20), (u>>8)&0xFFF, (36863-p)>>4 — identical to R7's k4h/k4scan
// chain. 8 replicated LDS sub-histograms dodge atomic contention; suffix-scan
// semantics (crossing bin + cumulative-above carry) replicated exactly.
__global__ __launch_bounds__(1024) void k4r(const float* __restrict__ skey,
                                            int* __restrict__ cut1g,
                                            int* __restrict__ cut2g,
                                            int* __restrict__ cut3g) {
    const int b = blockIdx.x, t = threadIdx.x;
    const int w8 = (t >> 6) & 7;
    __shared__ int h8[8][4096];       // 128 KB
    __shared__ int tsum[256];
    __shared__ int s_cut, s_prev;
    int cum = 0;
    int cuts[3];
#pragma unroll 1
    for (int level = 0; level < 3; ++level) {
        for (int k = t; k < 8 * 4096; k += 1024) ((int*)h8)[k] = 0;
        __syncthreads();
        for (int i = t; i < NA; i += 1024) {
            float sk = skey[(size_t)b * NA + i];
            unsigned u = __float_as_uint(sk);
            u = (u & 0x80000000u) ? ~u : (u | 0x80000000u);
            int b1 = (int)(u >> 20), b2 = (int)((u >> 8) & 0xFFFu);
            int digit; bool pred;
            if (level == 0)      { digit = b1;                pred = true; }
            else if (level == 1) { digit = b2;                pred = (b1 == cuts[0]); }
            else                 { digit = (36863 - i) >> 4;  pred = (b1 == cuts[0] && b2 == cuts[1]); }
            if (pred) atomicAdd(&h8[w8][digit], 1);
        }
        __syncthreads();
        for (int k = t; k < 4096; k += 1024) {
            int s = h8[0][k];
#pragma unroll
            for (int r = 1; r < 8; ++r) s += h8[r][k];
            h8[0][k] = s;
        }
        __syncthreads();
        // suffix-scan (threads 0..255, 16 bins each) — same crossing rule as R7 k4scan
        if (t < 256) {
            const int target = NIN_ - cum;
            int s = 0;
#pragma unroll
            for (int j = 0; j < 16; ++j) s += h8[0][t * 16 + j];
            tsum[t] = s;
        }
        __syncthreads();
        if (t == 0) {
            int run = 0;
            for (int tt = 255; tt >= 0; --tt) { int tmp = tsum[tt]; tsum[tt] = run; run += tmp; }
        }
        __syncthreads();
        if (t < 256) {
            const int target = NIN_ - cum;
            int run = tsum[t];
            for (int v = t * 16 + 15; v >= t * 16; --v) {
                int prev = run;
                run += h8[0][v];
                if (run >= target && prev < target) { s_cut = v; s_prev = prev; }
            }
        }
        __syncthreads();
        cuts[level] = s_cut;
        cum += s_prev;
        __syncthreads();
    }
    if (t == 0) { cut1g[b] = cuts[0]; cut2g[b] = cuts[1]; cut3g[b] = cuts[2]; }
}

// ---------------- K4c: compact candidate keys per 3-level cut --------------------------
// take = key-digits lexicographically >= (cut1,cut2,cut3). Level-3 bins hold <=16
// elements (idx unique) -> 6000 <= C < 6016 for ANY input distribution.
__global__ __launch_bounds__(256) void k4c_compact(const float* __restrict__ skey,
                                                   const int* __restrict__ cut1,
                                                   const int* __restrict__ cut2,
                                                   const int* __restrict__ cut3,
                                                   int* __restrict__ cnt,
                                                   unsigned long long* __restrict__ ckey) {
    const int p = blockIdx.x * 256 + threadIdx.x;
    const int b = blockIdx.y;
    float sk = skey[(size_t)b * NA + p];
    unsigned u = __float_as_uint(sk);
    u = (u & 0x80000000u) ? ~u : (u | 0x80000000u);
    int b1 = (int)(u >> 20), b2 = (int)((u >> 8) & 0xFFFu), b3 = (36863 - p) >> 4;
    int c1 = cut1[b], c2 = cut2[b], c3 = cut3[b];
    bool take = (b1 > c1) || (b1 == c1 && (b2 > c2 || (b2 == c2 && b3 >= c3)));
    if (take) {
        int pos = atomicAdd(&cnt[b], 1);
        // 48-bit key: score bits (monotone) then inverted index -> unique, matches
        // stable argsort(-s) tie-breaking. p recoverable: p = 36863 - (key & 0xFFFF).
        ckey[(size_t)b * NA + pos] =
            ((unsigned long long)u << 16) | (unsigned long long)(36863 - p);
    }
}

// ---------------- K4d: in-LDS bitonic sort of candidate keys, emit top-6000 ----------
__global__ __launch_bounds__(1024) void k4d_sort(const int* __restrict__ cnt,
                                                 const unsigned long long* __restrict__ ckey,
                                                 const float* __restrict__ rois4,
                                                 float* __restrict__ rois_s,
                                                 int* __restrict__ valid_s) {
    const int b = blockIdx.x, t = threadIdx.x;
    const int C = min(cnt[b], 8192);
    __shared__ unsigned long long keys[8192];
#pragma unroll
    for (int s = 0; s < 8; ++s) {
        int i = s * 1024 + t;
        keys[i] = (i < C) ? ckey[(size_t)b * NA + i] : 0ull;
    }
    __syncthreads();
    for (int k = 2; k <= 8192; k <<= 1) {
        for (int j = k >> 1; j > 0; j >>= 1) {
#pragma unroll
            for (int s = 0; s < 8; ++s) {
                int i = s * 1024 + t;
                int ixj = i ^ j;
                if (ixj > i) {
                    unsigned long long x = keys[i], y = keys[ixj];
                    bool up = ((i & k) == 0);            // descending overall
                    if (up ? (x < y) : (x > y)) { keys[i] = y; keys[ixj] = x; }
                }
            }
            __syncthreads();
        }
    }
    for (int r = t; r < NIN_; r += 1024) {
        unsigned long long key = keys[r];
        int p = 36863 - (int)(key & 0xFFFFull);
        const float4 bx = *(const float4*)&rois4[((size_t)b * NA + p) * 4];
        *(float4*)&rois_s[((size_t)b * NIN_ + r) * 4] = bx;
        valid_s[b * NIN_ + r] = ((unsigned)(key >> 16) != 0x007FFFFFu) ? 1 : 0;
    }
}

// ---------------- K5a: pairwise suppression bitmask matrix ----------------
__global__ __launch_bounds__(256) void k5_mat(const float* __restrict__ rois_s,
                                              unsigned long long* __restrict__ mat) {
    const int b = blockIdx.y, rb = blockIdx.x;
    const int t = threadIdx.x, wave = t >> 6, lane = t & 63;
    const int i = rb * 64 + lane;
    const bool rowok = (i < NIN_);
    __shared__ float cs[4][5][64];   // [wave][y1,x1,y2,x2,area][col]
    const float* bb = rois_s + (size_t)b * NIN_ * 4;

    float r0 = 0, r1 = 0, r2 = 0, r3 = 0, ra = 0;
    if (rowok) {
        float4 v = *(const float4*)&bb[(size_t)i * 4];
        r0 = v.x; r1 = v.y; r2 = v.z; r3 = v.w;
        ra = (v.z - v.x) * (v.w - v.y);
    }
    unsigned long long* mrow = mat + ((size_t)b * NIN_ + (size_t)(rowok ? i : 0)) * NW;

    if (rowok)
        for (int cb = wave; cb < rb; cb += 4) mrow[cb] = 0ull;

    for (int cb = rb + wave; cb < NW; cb += 4) {
        const int j0 = cb * 64;
        const int j  = j0 + lane;
        float4 v;
        if (j < NIN_) v = *(const float4*)&bb[(size_t)j * 4];
        else { v.x = 0; v.y = 0; v.z = 0; v.w = 0; }
        cs[wave][0][lane] = v.x; cs[wave][1][lane] = v.y;
        cs[wave][2][lane] = v.z; cs[wave][3][lane] = v.w;
        cs[wave][4][lane] = (v.z - v.x) * (v.w - v.y);
        unsigned long long wm = 0;
        if (rowok) {
#pragma unroll 8
            for (int k = 0; k < 64; ++k) {
                float yy1 = fmaxf(r0, cs[wave][0][k]), xx1 = fmaxf(r1, cs[wave][1][k]);
                float yy2 = fminf(r2, cs[wave][2][k]), xx2 = fminf(r3, cs[wave][3][k]);
                float inter = fmaxf(yy2 - yy1, 0.f) * fmaxf(xx2 - xx1, 0.f);
                float iou = inter / (ra + cs[wave][4][k] - inter + 1e-9f);
                int jj = j0 + k;
                if ((iou > 0.7f) && (jj > i) && (jj < NIN_)) wm |= (1ull << k);
            }
            mrow[cb] = wm;
        }
    }
}

// ---------------- K5b: serial greedy scan over bitmask ----------------
__global__ __launch_bounds__(64) void k5_scan(const unsigned long long* __restrict__ mat,
                                              const float* __restrict__ rois_s,
                                              const int* __restrict__ valid_s,
                                              float* __restrict__ out) {
    const int b = blockIdx.x, t = threadIdx.x;
    for (int k = t; k < NOUT2 * 4; k += 64) out[O_ROI + (size_t)b * NOUT2 * 4 + k] = 0.f;
    for (int k = t; k < NOUT2; k += 64) out[O_IDX + (size_t)b * NOUT2 + k] = (float)b;

    unsigned long long A = 0, B = 0;
    for (int w = 0; w < NW; ++w) {
        int i = w * 64 + t;
        int v = (i < NIN_) ? valid_s[b * NIN_ + i] : 0;
        unsigned long long m = __ballot(v == 0);
        if (w < 64) { if (t == w) A = m; }
        else        { if (t == w - 64) B = m; }
    }

    const unsigned long long* mb = mat + (size_t)b * NIN_ * NW;
    const float* bb = rois_s + (size_t)b * NIN_ * 4;
    int kept = 0;
    for (int w = 0; w < NW && kept < NOUT2; ++w) {
        unsigned long long cur = (w < 64) ? __shfl(A, w) : __shfl(B, w - 64);
        unsigned long long avail = ~cur;
        while (avail != 0ull && kept < NOUT2) {
            int bit = __builtin_ctzll(avail);
            int i = w * 64 + bit;
            if (t == 0) {
                float4 bx = *(const float4*)&bb[(size_t)i * 4];
                *(float4*)&out[O_ROI + ((size_t)b * NOUT2 + kept) * 4] = bx;
            }
            kept++;
            if (kept >= NOUT2) break;
            const unsigned long long* row = mb + (size_t)i * NW;
            unsigned long long rA = row[t];
            unsigned long long rB = (t < NW - 64) ? row[64 + t] : 0ull;
            A |= rA; B |= rB;
            unsigned long long rw = (w < 64) ? __shfl(rA, w) : __shfl(rB, w - 64);
            avail &= ~rw;
            avail &= ~(1ull << bit);
        }
    }
}

// ---------------- launch ----------------
extern "C" void kernel_launch(void* const* d_in, const int* in_sizes, int n_in,
                              void* d_out, int out_size, void* d_ws, size_t ws_size,
                              hipStream_t stream) {
    const float* x       = (const float*)d_in[0];
    const float* conv_w  = (const float*)d_in[1];
    const float* conv_b  = (const float*)d_in[2];
    const float* score_w = (const float*)d_in[3];
    const float* score_b = (const float*)d_in[4];
    const float* loc_w   = (const float*)d_in[5];
    const float* loc_b   = (const float*)d_in[6];
    float* out = (float*)d_out;
    float* ws  = (float*)d_ws;    // high-water 43.0 MB (same as R1-R7)

    f16* whi = (f16*)(ws + W_WHI);
    f16* wlo = (f16*)(ws + W_WLO);

    k0w<<<2359296 / 256, 256, 0, stream>>>(conv_w, whi, wlo);
    k1_mfma<<<dim3(32, 4, 4), 256, 0, stream>>>(x, whi, wlo, conv_b, ws + W_H);
    k2_conv1<<<dim3(64, 4), 256, 0, stream>>>(ws + W_H, score_w, score_b, loc_w, loc_b, out);
    // zero cnt+cuts (region aliases h -> zero AFTER K2)
    hipMemsetAsync(ws + W_CNT, 0, 128, stream);
    k3_prop<<<dim3(144, 4), 256, 0, stream>>>(out, ws + W_R4, ws + W_SK);
    k4r<<<BATCH, 1024, 0, stream>>>(ws + W_SK, (int*)(ws + W_CUT),
                                    (int*)(ws + W_CUT2), (int*)(ws + W_CUT3));
    k4c_compact<<<dim3(144, 4), 256, 0, stream>>>(ws + W_SK, (const int*)(ws + W_CUT),
                                                  (const int*)(ws + W_CUT2),
                                                  (const int*)(ws + W_CUT3),
                                                  (int*)(ws + W_CNT),
                                                  (unsigned long long*)(ws + W_CKEY));
    k4d_sort<<<BATCH, 1024, 0, stream>>>((const int*)(ws + W_CNT),
                                         (const unsigned long long*)(ws + W_CKEY),
                                         ws + W_R4, ws + W_RS, (int*)(ws + W_VS));
    k5_mat<<<dim3(NW, BATCH), 256, 0, stream>>>(ws + W_RS, (unsigned long long*)(ws + W_MAT));
    k5_scan<<<BATCH, 64, 0, stream>>>((const unsigned long long*)(ws + W_MAT),
                                      ws + W_RS, (const int*)(ws + W_VS), out);
}

// Round 9
// 977.968 us; speedup vs baseline: 1.0567x; 1.0567x over previous
//
#include <hip/hip_runtime.h>
#include <cstdint>
#include <cmath>

// ---------------- constants ----------------
namespace {
constexpr int BATCH = 4;
constexpr int CIN   = 512;
constexpr int CMID  = 512;
constexpr int HSZ   = 64, WSZ = 64, HWP = 4096;
constexpr int NA    = 36864;          // HW * 9 anchors
constexpr int NIN_  = 6000;
constexpr int NOUT2 = 300;
constexpr int NW    = 94;             // ceil(6000/64) u64 words per bitmask row

// d_out layout (float offsets)
constexpr size_t O_SC  = 0;           // rpn_scores (4,36864,2)
constexpr size_t O_LC  = 294912;      // rpn_locs   (4,36864,4)
constexpr size_t O_ROI = 884736;      // rois       (1200,4)
constexpr size_t O_IDX = 889536;      // roi_indices(1200)
constexpr size_t O_ANC = 890736;      // anchors    (36864,4)

// d_ws layout (float offsets). Phase A: h + w-split. Phase B (post-K2) aliases h.
// High-water = 10747904 floats = 43.0 MB (same as the proven R1-R8 layout).
constexpr size_t W_H    = 0;          // 8388608 floats (conv hidden, NCHW)
constexpr size_t W_WHI  = 8388608;    // 2359296 f16 W hi, [kk][co][ci]
constexpr size_t W_WLO  = 9568256;    // 2359296 f16 W lo (scaled 2048)
constexpr size_t W_R4   = 0;          // 589824  rois per anchor (aliases h)
constexpr size_t W_SK   = 589824;     // 147456  score keys (fg or -inf)
constexpr size_t W_CNT  = 753664;     // 4 ints   compact counter
constexpr size_t W_CUT  = 753668;     // 4 ints   cut1
constexpr size_t W_CUT2 = 753676;     // 4 ints
constexpr size_t W_CUT3 = 753684;     // 4 ints   (region W_CNT..753695 memset to 0)
constexpr size_t W_CKEY = 901184;     // 147456 u64 keys (8B aligned)
constexpr size_t W_RS   = 1196096;    // 96000  sorted rois (4,6000,4)
constexpr size_t W_VS   = 1292096;    // 24000 ints sorted validity
constexpr size_t W_MAT  = 1316096;    // 4*6000*94 u64 (suppression bits)
} // namespace

typedef _Float16 f16;
typedef __attribute__((ext_vector_type(4))) _Float16 f16x4;
typedef __attribute__((ext_vector_type(8))) _Float16 f16x8;
typedef __attribute__((ext_vector_type(4))) float f32x4;

// ---------------- K0w: split conv_w*64 into f16 hi/lo, layout [kk][co][ci] ----------------
__global__ __launch_bounds__(256) void k0w(const float* __restrict__ w,
                                           f16* __restrict__ whi, f16* __restrict__ wlo) {
    int o = blockIdx.x * 256 + threadIdx.x;     // 2359296 total
    int ci = o & 511;
    int r  = o >> 9;
    int co = r & 511;
    int kk = r >> 9;
    float f = w[(co * CIN + ci) * 9 + kk] * 64.0f;   // scale 64: keep hi out of f16-subnormals
    f16 hv = (f16)f;
    whi[o] = hv;
    wlo[o] = (f16)((f - (float)hv) * 2048.0f);       // lo scaled 2^11 into normal range
}

// ---------------- K1: 3x3 conv + bias + ReLU via f16-split MFMA (3 products) ----------
// R7's rolled ks-loop structure (120 VGPR, no spill — R8's full unroll spilled:
// WRITE_SIZE 33->111 MB) + R8's verified W-tile XOR swizzle (halves LDS bank
// conflicts; bijective per co-row -> bit-identical h).
__global__ __launch_bounds__(256, 2) void k1_mfma(const float* __restrict__ x,
                                                  const f16* __restrict__ gwh,
                                                  const f16* __restrict__ gwl,
                                                  const float* __restrict__ bias,
                                                  float* __restrict__ h) {
    const int pt = blockIdx.x, cg = blockIdx.y, b = blockIdx.z;
    const int y0 = pt * 2, co0 = cg * 128;
    const int t = threadIdx.x;
    const int wave = t >> 6, lane = t & 63;
    const int wrow = wave >> 1, wco = wave & 1;
    const int m = lane & 15, q = lane >> 4;

    // X tile: [hi/lo][(row*66 + col)*40 + ci]  (rows y0-1..y0+2, col = img_x+1, ci 0..31, pad 40)
    __shared__ __align__(16) f16 xs[2][4 * 66 * 40];
    // W tile: [slot][hi/lo][co*32 + (ci ^ swz(co))]
    __shared__ __align__(16) f16 wt[2][2][128 * 32];

    f32x4 acc1[4][4], acc2[4][4];
#pragma unroll
    for (int i = 0; i < 4; ++i)
#pragma unroll
        for (int j = 0; j < 4; ++j) { acc1[i][j] = (f32x4)0.0f; acc2[i][j] = (f32x4)0.0f; }

    // X staging roles
    const int cq = t & 7, srow = (t >> 3) & 3, cseg = t >> 5;
    const int gy = y0 - 1 + srow;
    const bool yok = (gy >= 0 && gy < HSZ);

    // zero the padding columns (img_x=-1 -> col 0, img_x=64 -> col 65); never rewritten
    if (t < 128) {
        int buf = t >> 6, rr = (t >> 4) & 3, cc = ((t >> 3) & 1) ? 65 : 0, cq2 = t & 7;
        f16x4 z = (f16x4)(f16)0.0f;
        *(f16x4*)&xs[buf][(rr * 66 + cc) * 40 + cq2 * 4] = z;
    }

    // W staging thread constants (2 strided slots of 256 cover 512 f16x8 tasks)
    int wbase[2], wpos[2];
#pragma unroll
    for (int s = 0; s < 2; ++s) {
        int idx = s * 256 + t;
        int co_l = idx >> 2, q8 = idx & 3;
        wbase[s] = (co0 + co_l) * 512 + q8 * 8;                       // gw offset (kk=0,chunk=0)
        wpos[s]  = co_l * 32 + ((q8 * 8) ^ (((co_l >> 1) & 3) << 3)); // swizzled LDS pos
    }

    // prologue: stage W(kk=0, chunk=0) into slot 0
#pragma unroll
    for (int s = 0; s < 2; ++s) {
        *(f16x8*)&wt[0][0][wpos[s]] = *(const f16x8*)&gwh[wbase[s]];
        *(f16x8*)&wt[0][1][wpos[s]] = *(const f16x8*)&gwl[wbase[s]];
    }

    // hoisted read base for B (swz depends only on m; nt*16 and wco*64 leave it unchanged)
    const int baseB = wco * 2048 + m * 32 + ((q * 8) ^ (((m >> 1) & 3) << 3));

    int chunk = 0, kk = 0;
    for (int ks = 0; ks < 144; ++ks) {
        const int slot = ks & 1;
        __syncthreads();   // all waves done with ks-1 compute -> safe to overwrite slot^1 / X

        if (kk == 0) {
            // stage X(chunk): thread = (cq, srow, cseg); 4 ci x 8 cols, split f16 hi/lo
            float vb[4][8];
            const float* xp = x + ((size_t)(b * CIN + chunk * 32 + cq * 4)) * HWP + gy * WSZ + cseg * 8;
#pragma unroll
            for (int i = 0; i < 4; ++i) {
                if (yok) {
                    float4 u0 = *(const float4*)(xp + (size_t)i * HWP);
                    float4 u1 = *(const float4*)(xp + (size_t)i * HWP + 4);
                    vb[i][0] = u0.x; vb[i][1] = u0.y; vb[i][2] = u0.z; vb[i][3] = u0.w;
                    vb[i][4] = u1.x; vb[i][5] = u1.y; vb[i][6] = u1.z; vb[i][7] = u1.w;
                } else {
#pragma unroll
                    for (int jj = 0; jj < 8; ++jj) vb[i][jj] = 0.0f;
                }
            }
#pragma unroll
            for (int j = 0; j < 8; ++j) {
                int c = (j + cq) & 7;            // k-rotation: spread LDS banks across lanes
                int col = cseg * 8 + c + 1;
                f16x4 hv, lv;
#pragma unroll
                for (int i = 0; i < 4; ++i) {
                    float f = vb[i][c];
                    f16 hf = (f16)f;
                    hv[i] = hf;
                    lv[i] = (f16)((f - (float)hf) * 2048.0f);
                }
                int base = (srow * 66 + col) * 40 + cq * 4;
                *(f16x4*)&xs[0][base] = hv;
                *(f16x4*)&xs[1][base] = lv;
            }
        }

        // prefetch-stage W(ks+1) into slot^1 (overlaps compute; consumed next iter)
        if (ks + 1 < 144) {
            int kk2 = kk + 1, ch2 = chunk;
            if (kk2 == 9) { kk2 = 0; ch2++; }
            const int gofs = kk2 * 262144 + ch2 * 32;
#pragma unroll
            for (int s = 0; s < 2; ++s) {
                int g = wbase[s] + gofs;
                *(f16x8*)&wt[slot ^ 1][0][wpos[s]] = *(const f16x8*)&gwh[g];
                *(f16x8*)&wt[slot ^ 1][1][wpos[s]] = *(const f16x8*)&gwl[g];
            }
        }

        if (kk == 0) __syncthreads();   // X(chunk) (and prologue W0) ready

        // compute shift kk with W[slot]
        const int ky = (kk >= 6) ? 2 : (kk >= 3) ? 1 : 0;
        const int kx = kk - ky * 3;
        const int rs = wrow + ky;

        f16x8 bh[4], bl[4], ah[4], al[4];
#pragma unroll
        for (int nt = 0; nt < 4; ++nt) {
            int off = baseB + nt * 512;
            bh[nt] = *(const f16x8*)&wt[slot][0][off];
            bl[nt] = *(const f16x8*)&wt[slot][1][off];
        }
#pragma unroll
        for (int ct = 0; ct < 4; ++ct) {
            int off = (rs * 66 + ct * 16 + m + kx) * 40 + q * 8;
            ah[ct] = *(const f16x8*)&xs[0][off];
            al[ct] = *(const f16x8*)&xs[1][off];
        }
#pragma unroll
        for (int ct = 0; ct < 4; ++ct)
#pragma unroll
            for (int nt = 0; nt < 4; ++nt) {
                acc1[ct][nt] = __builtin_amdgcn_mfma_f32_16x16x32_f16(ah[ct], bh[nt], acc1[ct][nt], 0, 0, 0);
                acc2[ct][nt] = __builtin_amdgcn_mfma_f32_16x16x32_f16(ah[ct], bl[nt], acc2[ct][nt], 0, 0, 0);
                acc2[ct][nt] = __builtin_amdgcn_mfma_f32_16x16x32_f16(al[ct], bh[nt], acc2[ct][nt], 0, 0, 0);
            }

        ++kk;
        if (kk == 9) { kk = 0; ++chunk; }
    }

    // epilogue: h = (acc1 + acc2*2^-11)*2^-6 + bias, relu
    const int y = y0 + wrow;
#pragma unroll
    for (int nt = 0; nt < 4; ++nt) {
        const int co = co0 + wco * 64 + nt * 16 + m;    // D: n = lane&15
        const float bv = bias[co];
        size_t rowbase = ((size_t)(b * CMID + co)) * HWP + y * WSZ;
#pragma unroll
        for (int ct = 0; ct < 4; ++ct) {
            float4 o;
            o.x = fmaxf((acc1[ct][nt][0] + acc2[ct][nt][0] * (1.0f / 2048.0f)) * (1.0f / 64.0f) + bv, 0.0f);
            o.y = fmaxf((acc1[ct][nt][1] + acc2[ct][nt][1] * (1.0f / 2048.0f)) * (1.0f / 64.0f) + bv, 0.0f);
            o.z = fmaxf((acc1[ct][nt][2] + acc2[ct][nt][2] * (1.0f / 2048.0f)) * (1.0f / 64.0f) + bv, 0.0f);
            o.w = fmaxf((acc1[ct][nt][3] + acc2[ct][nt][3] * (1.0f / 2048.0f)) * (1.0f / 64.0f) + bv, 0.0f);
            *(float4*)&h[rowbase + ct * 16 + q * 4] = o;   // D: m = q*4+reg -> img x
        }
    }
}

// ---------------- K2: 1x1 convs (score 18 + loc 36) -> d_out in NHWC-anchor layout ----------
__global__ __launch_bounds__(256) void k2_conv1(const float* __restrict__ h,
                                                const float* __restrict__ sw,
                                                const float* __restrict__ sb,
                                                const float* __restrict__ lw,
                                                const float* __restrict__ lb,
                                                float* __restrict__ out) {
    const int y = blockIdx.x;
    const int b = blockIdx.y;
    const int t = threadIdx.x;
    const int c4  = (t & 15) * 4;
    const int px4 = (t >> 4) * 4;
    __shared__ __align__(16) float hs[1024];        // [ci(16)][px(64)]
    __shared__ __align__(16) float wsm[16 * 68];    // [ci][c] padded

    float acc[4][4];
#pragma unroll
    for (int i = 0; i < 4; ++i)
#pragma unroll
        for (int j = 0; j < 4; ++j) acc[i][j] = 0.f;

    const int s_px = (t & 15) * 4;
    const int s_ci = t >> 4;
    for (int ci0 = 0; ci0 < CMID; ci0 += 16) {
        *(float4*)&hs[s_ci * 64 + s_px] =
            *(const float4*)&h[((size_t)(b * CMID + ci0 + s_ci)) * HWP + y * 64 + s_px];
#pragma unroll
        for (int k = 0; k < 4; ++k) {
            int idx = k * 256 + t;
            int ci = idx & 15, c = idx >> 4;
            float v = 0.f;
            if (c < 18) v = sw[c * 512 + ci0 + ci];
            else if (c < 54) v = lw[(c - 18) * 512 + ci0 + ci];
            wsm[ci * 68 + c] = v;
        }
        __syncthreads();
#pragma unroll
        for (int ci = 0; ci < 16; ++ci) {
            float4 hv = *(const float4*)&hs[ci * 64 + px4];
            float4 wv = *(const float4*)&wsm[ci * 68 + c4];
            acc[0][0] = fmaf(wv.x, hv.x, acc[0][0]);
            acc[0][1] = fmaf(wv.x, hv.y, acc[0][1]);
            acc[0][2] = fmaf(wv.x, hv.z, acc[0][2]);
            acc[0][3] = fmaf(wv.x, hv.w, acc[0][3]);
            acc[1][0] = fmaf(wv.y, hv.x, acc[1][0]);
            acc[1][1] = fmaf(wv.y, hv.y, acc[1][1]);
            acc[1][2] = fmaf(wv.y, hv.z, acc[1][2]);
            acc[1][3] = fmaf(wv.y, hv.w, acc[1][3]);
            acc[2][0] = fmaf(wv.z, hv.x, acc[2][0]);
            acc[2][1] = fmaf(wv.z, hv.y, acc[2][1]);
            acc[2][2] = fmaf(wv.z, hv.z, acc[2][2]);
            acc[2][3] = fmaf(wv.z, hv.w, acc[2][3]);
            acc[3][0] = fmaf(wv.w, hv.x, acc[3][0]);
            acc[3][1] = fmaf(wv.w, hv.y, acc[3][1]);
            acc[3][2] = fmaf(wv.w, hv.z, acc[3][2]);
            acc[3][3] = fmaf(wv.w, hv.w, acc[3][3]);
        }
        __syncthreads();
    }

#pragma unroll
    for (int cc = 0; cc < 4; ++cc) {
        int c = c4 + cc;
        if (c >= 54) break;
        float bv = (c < 18) ? sb[c] : lb[c - 18];
#pragma unroll
        for (int pp = 0; pp < 4; ++pp) {
            int px = y * 64 + px4 + pp;
            float v = acc[cc][pp] + bv;
            if (c < 18)
                out[O_SC + (size_t)b * 73728 + (size_t)px * 18 + c] = v;
            else
                out[O_LC + (size_t)b * 147456 + (size_t)px * 36 + (c - 18)] = v;
        }
    }
}

// ---------------- K3: anchors + softmax-fg + loc2bbox + clip ----------
__global__ __launch_bounds__(256) void k3_prop(float* __restrict__ out,
                                               float* __restrict__ rois4,
                                               float* __restrict__ skey) {
    const int t = threadIdx.x;
    const int p = blockIdx.x * 256 + t;
    const int b = blockIdx.y;
    const int px = p / 9;
    const int a  = p - px * 9;
    const int yy = px >> 6, xx = px & 63;
    const int ri = a / 3, si = a - ri * 3;
    const double rat[3] = {0.5, 1.0, 2.0};
    const double scl[3] = {8.0, 16.0, 32.0};
    double hhd = 16.0 * scl[si] * sqrt(rat[ri]);
    double wwd = 16.0 * scl[si] * sqrt(1.0 / rat[ri]);
    float a0 = (float)(8.0 - hhd / 2.0), a1 = (float)(8.0 - wwd / 2.0);
    float a2 = (float)(8.0 + hhd / 2.0), a3 = (float)(8.0 + wwd / 2.0);
    float sy = (float)(yy * 16), sx = (float)(xx * 16);
    float A0 = sy + a0, A1 = sx + a1, A2 = sy + a2, A3 = sx + a3;
    if (b == 0) {
        float4 av; av.x = A0; av.y = A1; av.z = A2; av.w = A3;
        *(float4*)&out[O_ANC + (size_t)p * 4] = av;
    }
    const float* sc = out + O_SC + (size_t)b * 73728 + (size_t)px * 18 + a * 2;
    float s0 = sc[0], s1 = sc[1];
    float mm = fmaxf(s0, s1);
    float e0 = expf(s0 - mm), e1 = expf(s1 - mm);
    float fg = e1 / (e0 + e1);
    const float* lc = out + O_LC + (size_t)b * 147456 + (size_t)px * 36 + a * 4;
    float dy = lc[0], dxv = lc[1], dh = lc[2], dwv = lc[3];
    float ah = A2 - A0, aw = A3 - A1;
    float cy = A0 + 0.5f * ah, cx = A1 + 0.5f * aw;
    float cty = dy * ah + cy, ctx = dxv * aw + cx;
    float th = expf(dh) * ah, tw = expf(dwv) * aw;
    float ry1 = cty - 0.5f * th, rx1 = ctx - 0.5f * tw;
    float ry2 = cty + 0.5f * th, rx2 = ctx + 0.5f * tw;
    float y1 = fminf(fmaxf(ry1, 0.f), 1024.f);
    float y2 = fminf(fmaxf(ry2, 0.f), 1024.f);
    float x1 = fminf(fmaxf(rx1, 0.f), 1024.f);
    float x2 = fminf(fmaxf(rx2, 0.f), 1024.f);
    bool valid = ((y2 - y1) >= 16.f) && ((x2 - x1) >= 16.f);
    float sk = valid ? fg : -__builtin_inff();
    float4 rv; rv.x = y1; rv.y = x1; rv.z = y2; rv.w = x2;
    *(float4*)&rois4[((size_t)b * NA + p) * 4] = rv;
    skey[(size_t)b * NA + p] = sk;
}

// ---------------- K4r: 3-level radix cut in one kernel (1 block/batch, 1024 thr) -------
__global__ __launch_bounds__(1024) void k4r(const float* __restrict__ skey,
                                            int* __restrict__ cut1g,
                                            int* __restrict__ cut2g,
                                            int* __restrict__ cut3g) {
    const int b = blockIdx.x, t = threadIdx.x;
    const int w8 = (t >> 6) & 7;
    __shared__ int h8[8][4096];       // 128 KB
    __shared__ int tsum[256];
    __shared__ int s_cut, s_prev;
    int cum = 0;
    int cuts[3];
#pragma unroll 1
    for (int level = 0; level < 3; ++level) {
        for (int k = t; k < 8 * 4096; k += 1024) ((int*)h8)[k] = 0;
        __syncthreads();
        for (int i = t; i < NA; i += 1024) {
            float sk = skey[(size_t)b * NA + i];
            unsigned u = __float_as_uint(sk);
            u = (u & 0x80000000u) ? ~u : (u | 0x80000000u);
            int b1 = (int)(u >> 20), b2 = (int)((u >> 8) & 0xFFFu);
            int digit; bool pred;
            if (level == 0)      { digit = b1;                pred = true; }
            else if (level == 1) { digit = b2;                pred = (b1 == cuts[0]); }
            else                 { digit = (36863 - i) >> 4;  pred = (b1 == cuts[0] && b2 == cuts[1]); }
            if (pred) atomicAdd(&h8[w8][digit], 1);
        }
        __syncthreads();
        for (int k = t; k < 4096; k += 1024) {
            int s = h8[0][k];
#pragma unroll
            for (int r = 1; r < 8; ++r) s += h8[r][k];
            h8[0][k] = s;
        }
        __syncthreads();
        if (t < 256) {
            int s = 0;
#pragma unroll
            for (int j = 0; j < 16; ++j) s += h8[0][t * 16 + j];
            tsum[t] = s;
        }
        __syncthreads();
        if (t == 0) {
            int run = 0;
            for (int tt = 255; tt >= 0; --tt) { int tmp = tsum[tt]; tsum[tt] = run; run += tmp; }
        }
        __syncthreads();
        if (t < 256) {
            const int target = NIN_ - cum;
            int run = tsum[t];
            for (int v = t * 16 + 15; v >= t * 16; --v) {
                int prev = run;
                run += h8[0][v];
                if (run >= target && prev < target) { s_cut = v; s_prev = prev; }
            }
        }
        __syncthreads();
        cuts[level] = s_cut;
        cum += s_prev;
        __syncthreads();
    }
    if (t == 0) { cut1g[b] = cuts[0]; cut2g[b] = cuts[1]; cut3g[b] = cuts[2]; }
}

// ---------------- K4c: compact candidate keys per 3-level cut --------------------------
__global__ __launch_bounds__(256) void k4c_compact(const float* __restrict__ skey,
                                                   const int* __restrict__ cut1,
                                                   const int* __restrict__ cut2,
                                                   const int* __restrict__ cut3,
                                                   int* __restrict__ cnt,
                                                   unsigned long long* __restrict__ ckey) {
    const int p = blockIdx.x * 256 + threadIdx.x;
    const int b = blockIdx.y;
    float sk = skey[(size_t)b * NA + p];
    unsigned u = __float_as_uint(sk);
    u = (u & 0x80000000u) ? ~u : (u | 0x80000000u);
    int b1 = (int)(u >> 20), b2 = (int)((u >> 8) & 0xFFFu), b3 = (36863 - p) >> 4;
    int c1 = cut1[b], c2 = cut2[b], c3 = cut3[b];
    bool take = (b1 > c1) || (b1 == c1 && (b2 > c2 || (b2 == c2 && b3 >= c3)));
    if (take) {
        int pos = atomicAdd(&cnt[b], 1);
        // 48-bit key: score bits (monotone) then inverted index -> unique, matches
        // stable argsort(-s) tie-breaking. p recoverable: p = 36863 - (key & 0xFFFF).
        ckey[(size_t)b * NA + pos] =
            ((unsigned long long)u << 16) | (unsigned long long)(36863 - p);
    }
}

// ---------------- K4d: in-LDS bitonic sort of candidate keys, emit top-6000 ----------
// C < 6016 proven by the 3-level radix cut -> fits the 8192 network for ANY input.
__global__ __launch_bounds__(1024) void k4d_sort(const int* __restrict__ cnt,
                                                 const unsigned long long* __restrict__ ckey,
                                                 const float* __restrict__ rois4,
                                                 float* __restrict__ rois_s,
                                                 int* __restrict__ valid_s) {
    const int b = blockIdx.x, t = threadIdx.x;
    const int C = min(cnt[b], 8192);
    __shared__ unsigned long long keys[8192];
#pragma unroll
    for (int s = 0; s < 8; ++s) {
        int i = s * 1024 + t;
        keys[i] = (i < C) ? ckey[(size_t)b * NA + i] : 0ull;
    }
    __syncthreads();
    for (int k = 2; k <= 8192; k <<= 1) {
        for (int j = k >> 1; j > 0; j >>= 1) {
#pragma unroll
            for (int s = 0; s < 8; ++s) {
                int i = s * 1024 + t;
                int ixj = i ^ j;
                if (ixj > i) {
                    unsigned long long x = keys[i], y = keys[ixj];
                    bool up = ((i & k) == 0);            // descending overall
                    if (up ? (x < y) : (x > y)) { keys[i] = y; keys[ixj] = x; }
                }
            }
            __syncthreads();
        }
    }
    for (int r = t; r < NIN_; r += 1024) {
        unsigned long long key = keys[r];
        int p = 36863 - (int)(key & 0xFFFFull);
        const float4 bx = *(const float4*)&rois4[((size_t)b * NA + p) * 4];
        *(float4*)&rois_s[((size_t)b * NIN_ + r) * 4] = bx;
        valid_s[b * NIN_ + r] = ((unsigned)(key >> 16) != 0x007FFFFFu) ? 1 : 0;
    }
}

// ---------------- K5a: pairwise suppression bitmask matrix ----------------
__global__ __launch_bounds__(256) void k5_mat(const float* __restrict__ rois_s,
                                              unsigned long long* __restrict__ mat) {
    const int b = blockIdx.y, rb = blockIdx.x;
    const int t = threadIdx.x, wave = t >> 6, lane = t & 63;
    const int i = rb * 64 + lane;
    const bool rowok = (i < NIN_);
    __shared__ float cs[4][5][64];   // [wave][y1,x1,y2,x2,area][col]
    const float* bb = rois_s + (size_t)b * NIN_ * 4;

    float r0 = 0, r1 = 0, r2 = 0, r3 = 0, ra = 0;
    if (rowok) {
        float4 v = *(const float4*)&bb[(size_t)i * 4];
        r0 = v.x; r1 = v.y; r2 = v.z; r3 = v.w;
        ra = (v.z - v.x) * (v.w - v.y);
    }
    unsigned long long* mrow = mat + ((size_t)b * NIN_ + (size_t)(rowok ? i : 0)) * NW;

    if (rowok)
        for (int cb = wave; cb < rb; cb += 4) mrow[cb] = 0ull;

    for (int cb = rb + wave; cb < NW; cb += 4) {
        const int j0 = cb * 64;
        const int j  = j0 + lane;
        float4 v;
        if (j < NIN_) v = *(const float4*)&bb[(size_t)j * 4];
        else { v.x = 0; v.y = 0; v.z = 0; v.w = 0; }
        cs[wave][0][lane] = v.x; cs[wave][1][lane] = v.y;
        cs[wave][2][lane] = v.z; cs[wave][3][lane] = v.w;
        cs[wave][4][lane] = (v.z - v.x) * (v.w - v.y);
        unsigned long long wm = 0;
        if (rowok) {
#pragma unroll 8
            for (int k = 0; k < 64; ++k) {
                float yy1 = fmaxf(r0, cs[wave][0][k]), xx1 = fmaxf(r1, cs[wave][1][k]);
                float yy2 = fminf(r2, cs[wave][2][k]), xx2 = fminf(r3, cs[wave][3][k]);
                float inter = fmaxf(yy2 - yy1, 0.f) * fmaxf(xx2 - xx1, 0.f);
                float iou = inter / (ra + cs[wave][4][k] - inter + 1e-9f);
                int jj = j0 + k;
                if ((iou > 0.7f) && (jj > i) && (jj < NIN_)) wm |= (1ull << k);
            }
            mrow[cb] = wm;
        }
    }
}

// ---------------- K5b: serial greedy scan over bitmask ----------------
__global__ __launch_bounds__(64) void k5_scan(const unsigned long long* __restrict__ mat,
                                              const float* __restrict__ rois_s,
                                              const int* __restrict__ valid_s,
                                              float* __restrict__ out) {
    const int b = blockIdx.x, t = threadIdx.x;
    for (int k = t; k < NOUT2 * 4; k += 64) out[O_ROI + (size_t)b * NOUT2 * 4 + k] = 0.f;
    for (int k = t; k < NOUT2; k += 64) out[O_IDX + (size_t)b * NOUT2 + k] = (float)b;

    unsigned long long A = 0, B = 0;
    for (int w = 0; w < NW; ++w) {
        int i = w * 64 + t;
        int v = (i < NIN_) ? valid_s[b * NIN_ + i] : 0;
        unsigned long long m = __ballot(v == 0);
        if (w < 64) { if (t == w) A = m; }
        else        { if (t == w - 64) B = m; }
    }

    const unsigned long long* mb = mat + (size_t)b * NIN_ * NW;
    const float* bb = rois_s + (size_t)b * NIN_ * 4;
    int kept = 0;
    for (int w = 0; w < NW && kept < NOUT2; ++w) {
        unsigned long long cur = (w < 64) ? __shfl(A, w) : __shfl(B, w - 64);
        unsigned long long avail = ~cur;
        while (avail != 0ull && kept < NOUT2) {
            int bit = __builtin_ctzll(avail);
            int i = w * 64 + bit;
            if (t == 0) {
                float4 bx = *(const float4*)&bb[(size_t)i * 4];
                *(float4*)&out[O_ROI + ((size_t)b * NOUT2 + kept) * 4] = bx;
            }
            kept++;
            if (kept >= NOUT2) break;
            const unsigned long long* row = mb + (size_t)i * NW;
            unsigned long long rA = row[t];
            unsigned long long rB = (t < NW - 64) ? row[64 + t] : 0ull;
            A |= rA; B |= rB;
            unsigned long long rw = (w < 64) ? __shfl(rA, w) : __shfl(rB, w - 64);
            avail &= ~rw;
            avail &= ~(1ull << bit);
        }
    }
}

// ---------------- launch ----------------
extern "C" void kernel_launch(void* const* d_in, const int* in_sizes, int n_in,
                              void* d_out, int out_size, void* d_ws, size_t ws_size,
                              hipStream_t stream) {
    const float* x       = (const float*)d_in[0];
    const float* conv_w  = (const float*)d_in[1];
    const float* conv_b  = (const float*)d_in[2];
    const float* score_w = (const float*)d_in[3];
    const float* score_b = (const float*)d_in[4];
    const float* loc_w   = (const float*)d_in[5];
    const float* loc_b   = (const float*)d_in[6];
    float* out = (float*)d_out;
    float* ws  = (float*)d_ws;    // high-water 43.0 MB (same as R1-R8)

    f16* whi = (f16*)(ws + W_WHI);
    f16* wlo = (f16*)(ws + W_WLO);

    k0w<<<2359296 / 256, 256, 0, stream>>>(conv_w, whi, wlo);
    k1_mfma<<<dim3(32, 4, 4), 256, 0, stream>>>(x, whi, wlo, conv_b, ws + W_H);
    k2_conv1<<<dim3(64, 4), 256, 0, stream>>>(ws + W_H, score_w, score_b, loc_w, loc_b, out);
    // zero cnt+cuts (region aliases h -> zero AFTER K2)
    hipMemsetAsync(ws + W_CNT, 0, 128, stream);
    k3_prop<<<dim3(144, 4), 256, 0, stream>>>(out, ws + W_R4, ws + W_SK);
    k4r<<<BATCH, 1024, 0, stream>>>(ws + W_SK, (int*)(ws + W_CUT),
                                    (int*)(ws + W_CUT2), (int*)(ws + W_CUT3));
    k4c_compact<<<dim3(144, 4), 256, 0, stream>>>(ws + W_SK, (const int*)(ws + W_CUT),
                                                  (const int*)(ws + W_CUT2),
                                                  (const int*)(ws + W_CUT3),
                                                  (int*)(ws + W_CNT),
                                                  (unsigned long long*)(ws + W_CKEY));
    k4d_sort<<<BATCH, 1024, 0, stream>>>((const int*)(ws + W_CNT),
                                         (const unsigned long long*)(ws + W_CKEY),
                                         ws + W_R4, ws + W_RS, (int*)(ws + W_VS));
    k5_mat<<<dim3(NW, BATCH), 256, 0, stream>>>(ws + W_RS, (unsigned long long*)(ws + W_MAT));
    k5_scan<<<BATCH, 64, 0, stream>>>((const unsigned long long*)(ws + W_MAT),
                                      ws + W_RS, (const int*)(ws + W_VS), out);
}

// Round 10
// 894.571 us; speedup vs baseline: 1.1552x; 1.0932x over previous
//
#include <hip/hip_runtime.h>
#include <cstdint>
#include <cmath>

// ---------------- constants ----------------
namespace {
constexpr int BATCH = 4;
constexpr int CIN   = 512;
constexpr int CMID  = 512;
constexpr int HSZ   = 64, WSZ = 64, HWP = 4096;
constexpr int NA    = 36864;          // HW * 9 anchors
constexpr int NIN_  = 6000;
constexpr int NOUT2 = 300;
constexpr int NW    = 94;             // ceil(6000/64) u64 words per bitmask row

// d_out layout (float offsets)
constexpr size_t O_SC  = 0;           // rpn_scores (4,36864,2)
constexpr size_t O_LC  = 294912;      // rpn_locs   (4,36864,4)
constexpr size_t O_ROI = 884736;      // rois       (1200,4)
constexpr size_t O_IDX = 889536;      // roi_indices(1200)
constexpr size_t O_ANC = 890736;      // anchors    (36864,4)

// d_ws layout (float offsets). Phase A: h + w-split (+ optional x-split).
// Base high-water 43.0 MB (proven R1-R9); with x-split 76.5 MB (ws_size-gated).
constexpr size_t W_H    = 0;          // 8388608 floats (conv hidden, NCHW)
constexpr size_t W_WHI  = 8388608;    // 2359296 f16 W hi, [kk][co][ci]
constexpr size_t W_WLO  = 9568256;    // 2359296 f16 W lo (scaled 2048)
constexpr size_t W_XSP  = 10747904;   // 16777216 f16 X split [b][chunk][px][ciq(hi4,lo4)]
constexpr size_t W_END_PS = 19136512; // high-water (floats) when x-split enabled
constexpr size_t W_R4   = 0;          // 589824  rois per anchor (aliases h)
constexpr size_t W_SK   = 589824;     // 147456  score keys (fg or -inf)
constexpr size_t W_CNT  = 753664;     // 4 ints   compact counter
constexpr size_t W_CKEY = 901184;     // 147456 u64 keys (8B aligned)
constexpr size_t W_RS   = 1196096;    // 96000  sorted rois (4,6000,4)
constexpr size_t W_VS   = 1292096;    // 24000 ints sorted validity
constexpr size_t W_MAT  = 1316096;    // 4*6000*94 u64 (suppression bits)
} // namespace

typedef _Float16 f16;
typedef __attribute__((ext_vector_type(4))) _Float16 f16x4;
typedef __attribute__((ext_vector_type(8))) _Float16 f16x8;
typedef __attribute__((ext_vector_type(4))) float f32x4;

// ---------------- K0w: split conv_w*64 into f16 hi/lo, layout [kk][co][ci] ----------------
__global__ __launch_bounds__(256) void k0w(const float* __restrict__ w,
                                           f16* __restrict__ whi, f16* __restrict__ wlo) {
    int o = blockIdx.x * 256 + threadIdx.x;     // 2359296 total
    int ci = o & 511;
    int r  = o >> 9;
    int co = r & 511;
    int kk = r >> 9;
    float f = w[(co * CIN + ci) * 9 + kk] * 64.0f;   // scale 64: keep hi out of f16-subnormals
    f16 hv = (f16)f;
    whi[o] = hv;
    wlo[o] = (f16)((f - (float)hv) * 2048.0f);       // lo scaled 2^11 into normal range
}

// ---------------- K0x: pre-split X into f16 hi/lo, layout [b][chunk][px][ciq(hi4,lo4)] ----
// Moves k1's per-chunk cvt chains into one massively-parallel pass. Bit-identical
// split values (same expression as the in-k1 path).
__global__ __launch_bounds__(256) void k0x(const float* __restrict__ x,
                                           f16* __restrict__ xsp) {
    const int pt = blockIdx.x, ch = blockIdx.y, b = blockIdx.z, t = threadIdx.x;
    __shared__ float ld[32 * 261];   // [ci][px] pad 261 (odd) -> conflict-free column reads
    const int px0 = pt * 256;
    const int lpx = (t & 63) * 4, lc0 = t >> 6;
#pragma unroll
    for (int r = 0; r < 8; ++r) {
        int ci = r * 4 + lc0;
        float4 v = *(const float4*)&x[((size_t)(b * 512 + ch * 32 + ci)) * 4096 + px0 + lpx];
        float* d = &ld[ci * 261 + lpx];
        d[0] = v.x; d[1] = v.y; d[2] = v.z; d[3] = v.w;
    }
    __syncthreads();
    size_t ob = ((size_t)(b * 16 + ch) * 4096 + px0 + t) * 64;
#pragma unroll
    for (int cqx = 0; cqx < 8; ++cqx) {
        f16x8 o;
#pragma unroll
        for (int i = 0; i < 4; ++i) {
            float f = ld[(cqx * 4 + i) * 261 + t];
            f16 hf = (f16)f;
            o[i]     = hf;
            o[4 + i] = (f16)((f - (float)hf) * 2048.0f);
        }
        *(f16x8*)&xsp[ob + cqx * 8] = o;
    }
}

// ---------------- K1: 3x3 conv + bias + ReLU via f16-split MFMA (3 products) ----------
// R9-proven rolled structure + W-tile XOR swizzle. PS=true: X staging reads the
// pre-split planes (pure loads, no cvt). Same MFMA sequence -> bit-identical h.
template <bool PS>
__global__ __launch_bounds__(256, 2) void k1_mfma(const float* __restrict__ x,
                                                  const f16* __restrict__ xsp,
                                                  const f16* __restrict__ gwh,
                                                  const f16* __restrict__ gwl,
                                                  const float* __restrict__ bias,
                                                  float* __restrict__ h) {
    const int pt = blockIdx.x, cg = blockIdx.y, b = blockIdx.z;
    const int y0 = pt * 2, co0 = cg * 128;
    const int t = threadIdx.x;
    const int wave = t >> 6, lane = t & 63;
    const int wrow = wave >> 1, wco = wave & 1;
    const int m = lane & 15, q = lane >> 4;

    __shared__ __align__(16) f16 xs[2][4 * 66 * 40];
    __shared__ __align__(16) f16 wt[2][2][128 * 32];

    f32x4 acc1[4][4], acc2[4][4];
#pragma unroll
    for (int i = 0; i < 4; ++i)
#pragma unroll
        for (int j = 0; j < 4; ++j) { acc1[i][j] = (f32x4)0.0f; acc2[i][j] = (f32x4)0.0f; }

    const int cq = t & 7, srow = (t >> 3) & 3, cseg = t >> 5;
    const int gy = y0 - 1 + srow;
    const bool yok = (gy >= 0 && gy < HSZ);

    if (t < 128) {
        int buf = t >> 6, rr = (t >> 4) & 3, cc = ((t >> 3) & 1) ? 65 : 0, cq2 = t & 7;
        f16x4 z = (f16x4)(f16)0.0f;
        *(f16x4*)&xs[buf][(rr * 66 + cc) * 40 + cq2 * 4] = z;
    }

    int wbase[2], wpos[2];
#pragma unroll
    for (int s = 0; s < 2; ++s) {
        int idx = s * 256 + t;
        int co_l = idx >> 2, q8 = idx & 3;
        wbase[s] = (co0 + co_l) * 512 + q8 * 8;
        wpos[s]  = co_l * 32 + ((q8 * 8) ^ (((co_l >> 1) & 3) << 3));
    }
#pragma unroll
    for (int s = 0; s < 2; ++s) {
        *(f16x8*)&wt[0][0][wpos[s]] = *(const f16x8*)&gwh[wbase[s]];
        *(f16x8*)&wt[0][1][wpos[s]] = *(const f16x8*)&gwl[wbase[s]];
    }

    const int baseB = wco * 2048 + m * 32 + ((q * 8) ^ (((m >> 1) & 3) << 3));

    int chunk = 0, kk = 0;
    for (int ks = 0; ks < 144; ++ks) {
        const int slot = ks & 1;
        __syncthreads();

        if (kk == 0) {
            if (PS) {
                const f16* xb = xsp + (((size_t)(b * 16 + chunk) * 4096 + (size_t)(gy < 0 ? 0 : gy) * 64) * 64);
#pragma unroll
                for (int j = 0; j < 8; ++j) {
                    int c = (j + cq) & 7;
                    int col = cseg * 8 + c + 1;
                    f16x8 v = (f16x8)(f16)0.0f;
                    if (yok) v = *(const f16x8*)&xb[(size_t)(cseg * 8 + c) * 64 + cq * 8];
                    int base = (srow * 66 + col) * 40 + cq * 4;
                    *(f16x4*)&xs[0][base] = __builtin_shufflevector(v, v, 0, 1, 2, 3);
                    *(f16x4*)&xs[1][base] = __builtin_shufflevector(v, v, 4, 5, 6, 7);
                }
            } else {
                float vb[4][8];
                const float* xp = x + ((size_t)(b * CIN + chunk * 32 + cq * 4)) * HWP + gy * WSZ + cseg * 8;
#pragma unroll
                for (int i = 0; i < 4; ++i) {
                    if (yok) {
                        float4 u0 = *(const float4*)(xp + (size_t)i * HWP);
                        float4 u1 = *(const float4*)(xp + (size_t)i * HWP + 4);
                        vb[i][0] = u0.x; vb[i][1] = u0.y; vb[i][2] = u0.z; vb[i][3] = u0.w;
                        vb[i][4] = u1.x; vb[i][5] = u1.y; vb[i][6] = u1.z; vb[i][7] = u1.w;
                    } else {
#pragma unroll
                        for (int jj = 0; jj < 8; ++jj) vb[i][jj] = 0.0f;
                    }
                }
#pragma unroll
                for (int j = 0; j < 8; ++j) {
                    int c = (j + cq) & 7;
                    int col = cseg * 8 + c + 1;
                    f16x4 hv, lv;
#pragma unroll
                    for (int i = 0; i < 4; ++i) {
                        float f = vb[i][c];
                        f16 hf = (f16)f;
                        hv[i] = hf;
                        lv[i] = (f16)((f - (float)hf) * 2048.0f);
                    }
                    int base = (srow * 66 + col) * 40 + cq * 4;
                    *(f16x4*)&xs[0][base] = hv;
                    *(f16x4*)&xs[1][base] = lv;
                }
            }
        }

        if (ks + 1 < 144) {
            int kk2 = kk + 1, ch2 = chunk;
            if (kk2 == 9) { kk2 = 0; ch2++; }
            const int gofs = kk2 * 262144 + ch2 * 32;
#pragma unroll
            for (int s = 0; s < 2; ++s) {
                int g = wbase[s] + gofs;
                *(f16x8*)&wt[slot ^ 1][0][wpos[s]] = *(const f16x8*)&gwh[g];
                *(f16x8*)&wt[slot ^ 1][1][wpos[s]] = *(const f16x8*)&gwl[g];
            }
        }

        if (kk == 0) __syncthreads();

        const int ky = (kk >= 6) ? 2 : (kk >= 3) ? 1 : 0;
        const int kx = kk - ky * 3;
        const int rs = wrow + ky;

        f16x8 bh[4], bl[4], ah[4], al[4];
#pragma unroll
        for (int nt = 0; nt < 4; ++nt) {
            int off = baseB + nt * 512;
            bh[nt] = *(const f16x8*)&wt[slot][0][off];
            bl[nt] = *(const f16x8*)&wt[slot][1][off];
        }
#pragma unroll
        for (int ct = 0; ct < 4; ++ct) {
            int off = (rs * 66 + ct * 16 + m + kx) * 40 + q * 8;
            ah[ct] = *(const f16x8*)&xs[0][off];
            al[ct] = *(const f16x8*)&xs[1][off];
        }
#pragma unroll
        for (int ct = 0; ct < 4; ++ct)
#pragma unroll
            for (int nt = 0; nt < 4; ++nt) {
                acc1[ct][nt] = __builtin_amdgcn_mfma_f32_16x16x32_f16(ah[ct], bh[nt], acc1[ct][nt], 0, 0, 0);
                acc2[ct][nt] = __builtin_amdgcn_mfma_f32_16x16x32_f16(ah[ct], bl[nt], acc2[ct][nt], 0, 0, 0);
                acc2[ct][nt] = __builtin_amdgcn_mfma_f32_16x16x32_f16(al[ct], bh[nt], acc2[ct][nt], 0, 0, 0);
            }

        ++kk;
        if (kk == 9) { kk = 0; ++chunk; }
    }

    const int y = y0 + wrow;
#pragma unroll
    for (int nt = 0; nt < 4; ++nt) {
        const int co = co0 + wco * 64 + nt * 16 + m;
        const float bv = bias[co];
        size_t rowbase = ((size_t)(b * CMID + co)) * HWP + y * WSZ;
#pragma unroll
        for (int ct = 0; ct < 4; ++ct) {
            float4 o;
            o.x = fmaxf((acc1[ct][nt][0] + acc2[ct][nt][0] * (1.0f / 2048.0f)) * (1.0f / 64.0f) + bv, 0.0f);
            o.y = fmaxf((acc1[ct][nt][1] + acc2[ct][nt][1] * (1.0f / 2048.0f)) * (1.0f / 64.0f) + bv, 0.0f);
            o.z = fmaxf((acc1[ct][nt][2] + acc2[ct][nt][2] * (1.0f / 2048.0f)) * (1.0f / 64.0f) + bv, 0.0f);
            o.w = fmaxf((acc1[ct][nt][3] + acc2[ct][nt][3] * (1.0f / 2048.0f)) * (1.0f / 64.0f) + bv, 0.0f);
            *(float4*)&h[rowbase + ct * 16 + q * 4] = o;
        }
    }
}

// ---------------- K2: 1x1 convs (score 18 + loc 36) -> d_out in NHWC-anchor layout ----------
__global__ __launch_bounds__(256) void k2_conv1(const float* __restrict__ h,
                                                const float* __restrict__ sw,
                                                const float* __restrict__ sb,
                                                const float* __restrict__ lw,
                                                const float* __restrict__ lb,
                                                float* __restrict__ out) {
    const int y = blockIdx.x;
    const int b = blockIdx.y;
    const int t = threadIdx.x;
    const int c4  = (t & 15) * 4;
    const int px4 = (t >> 4) * 4;
    __shared__ __align__(16) float hs[1024];
    __shared__ __align__(16) float wsm[16 * 68];

    float acc[4][4];
#pragma unroll
    for (int i = 0; i < 4; ++i)
#pragma unroll
        for (int j = 0; j < 4; ++j) acc[i][j] = 0.f;

    const int s_px = (t & 15) * 4;
    const int s_ci = t >> 4;
    for (int ci0 = 0; ci0 < CMID; ci0 += 16) {
        *(float4*)&hs[s_ci * 64 + s_px] =
            *(const float4*)&h[((size_t)(b * CMID + ci0 + s_ci)) * HWP + y * 64 + s_px];
#pragma unroll
        for (int k = 0; k < 4; ++k) {
            int idx = k * 256 + t;
            int ci = idx & 15, c = idx >> 4;
            float v = 0.f;
            if (c < 18) v = sw[c * 512 + ci0 + ci];
            else if (c < 54) v = lw[(c - 18) * 512 + ci0 + ci];
            wsm[ci * 68 + c] = v;
        }
        __syncthreads();
#pragma unroll
        for (int ci = 0; ci < 16; ++ci) {
            float4 hv = *(const float4*)&hs[ci * 64 + px4];
            float4 wv = *(const float4*)&wsm[ci * 68 + c4];
            acc[0][0] = fmaf(wv.x, hv.x, acc[0][0]);
            acc[0][1] = fmaf(wv.x, hv.y, acc[0][1]);
            acc[0][2] = fmaf(wv.x, hv.z, acc[0][2]);
            acc[0][3] = fmaf(wv.x, hv.w, acc[0][3]);
            acc[1][0] = fmaf(wv.y, hv.x, acc[1][0]);
            acc[1][1] = fmaf(wv.y, hv.y, acc[1][1]);
            acc[1][2] = fmaf(wv.y, hv.z, acc[1][2]);
            acc[1][3] = fmaf(wv.y, hv.w, acc[1][3]);
            acc[2][0] = fmaf(wv.z, hv.x, acc[2][0]);
            acc[2][1] = fmaf(wv.z, hv.y, acc[2][1]);
            acc[2][2] = fmaf(wv.z, hv.z, acc[2][2]);
            acc[2][3] = fmaf(wv.z, hv.w, acc[2][3]);
            acc[3][0] = fmaf(wv.w, hv.x, acc[3][0]);
            acc[3][1] = fmaf(wv.w, hv.y, acc[3][1]);
            acc[3][2] = fmaf(wv.w, hv.z, acc[3][2]);
            acc[3][3] = fmaf(wv.w, hv.w, acc[3][3]);
        }
        __syncthreads();
    }

#pragma unroll
    for (int cc = 0; cc < 4; ++cc) {
        int c = c4 + cc;
        if (c >= 54) break;
        float bv = (c < 18) ? sb[c] : lb[c - 18];
#pragma unroll
        for (int pp = 0; pp < 4; ++pp) {
            int px = y * 64 + px4 + pp;
            float v = acc[cc][pp] + bv;
            if (c < 18)
                out[O_SC + (size_t)b * 73728 + (size_t)px * 18 + c] = v;
            else
                out[O_LC + (size_t)b * 147456 + (size_t)px * 36 + (c - 18)] = v;
        }
    }
}

// ---------------- K3: anchors + softmax-fg + loc2bbox + clip ----------
__global__ __launch_bounds__(256) void k3_prop(float* __restrict__ out,
                                               float* __restrict__ rois4,
                                               float* __restrict__ skey) {
    const int t = threadIdx.x;
    const int p = blockIdx.x * 256 + t;
    const int b = blockIdx.y;
    const int px = p / 9;
    const int a  = p - px * 9;
    const int yy = px >> 6, xx = px & 63;
    const int ri = a / 3, si = a - ri * 3;
    const double rat[3] = {0.5, 1.0, 2.0};
    const double scl[3] = {8.0, 16.0, 32.0};
    double hhd = 16.0 * scl[si] * sqrt(rat[ri]);
    double wwd = 16.0 * scl[si] * sqrt(1.0 / rat[ri]);
    float a0 = (float)(8.0 - hhd / 2.0), a1 = (float)(8.0 - wwd / 2.0);
    float a2 = (float)(8.0 + hhd / 2.0), a3 = (float)(8.0 + wwd / 2.0);
    float sy = (float)(yy * 16), sx = (float)(xx * 16);
    float A0 = sy + a0, A1 = sx + a1, A2 = sy + a2, A3 = sx + a3;
    if (b == 0) {
        float4 av; av.x = A0; av.y = A1; av.z = A2; av.w = A3;
        *(float4*)&out[O_ANC + (size_t)p * 4] = av;
    }
    const float* sc = out + O_SC + (size_t)b * 73728 + (size_t)px * 18 + a * 2;
    float s0 = sc[0], s1 = sc[1];
    float mm = fmaxf(s0, s1);
    float e0 = expf(s0 - mm), e1 = expf(s1 - mm);
    float fg = e1 / (e0 + e1);
    const float* lc = out + O_LC + (size_t)b * 147456 + (size_t)px * 36 + a * 4;
    float dy = lc[0], dxv = lc[1], dh = lc[2], dwv = lc[3];
    float ah = A2 - A0, aw = A3 - A1;
    float cy = A0 + 0.5f * ah, cx = A1 + 0.5f * aw;
    float cty = dy * ah + cy, ctx = dxv * aw + cx;
    float th = expf(dh) * ah, tw = expf(dwv) * aw;
    float ry1 = cty - 0.5f * th, rx1 = ctx - 0.5f * tw;
    float ry2 = cty + 0.5f * th, rx2 = ctx + 0.5f * tw;
    float y1 = fminf(fmaxf(ry1, 0.f), 1024.f);
    float y2 = fminf(fmaxf(ry2, 0.f), 1024.f);
    float x1 = fminf(fmaxf(rx1, 0.f), 1024.f);
    float x2 = fminf(fmaxf(rx2, 0.f), 1024.f);
    bool valid = ((y2 - y1) >= 16.f) && ((x2 - x1) >= 16.f);
    float sk = valid ? fg : -__builtin_inff();
    float4 rv; rv.x = y1; rv.y = x1; rv.z = y2; rv.w = x2;
    *(float4*)&rois4[((size_t)b * NA + p) * 4] = rv;
    skey[(size_t)b * NA + p] = sk;
}

// ---------------- K4rc: 3-level radix cut + fused compaction (1 block/batch) ----------
// Identical cut semantics to R8/R9's k4r; compaction (formerly k4c) fused with an
// LDS counter (order of ckey irrelevant — rank fixes it). 6000 <= C < 6016 proven.
__global__ __launch_bounds__(1024) void k4rc(const float* __restrict__ skey,
                                             int* __restrict__ cnt,
                                             unsigned long long* __restrict__ ckey) {
    const int b = blockIdx.x, t = threadIdx.x;
    const int w8 = (t >> 6) & 7;
    __shared__ int h8[8][4096];       // 128 KB
    __shared__ int tsum[256];
    __shared__ int s_cut, s_prev, lcnt;
    int cum = 0;
    int cuts[3];
#pragma unroll 1
    for (int level = 0; level < 3; ++level) {
        for (int k = t; k < 8 * 4096; k += 1024) ((int*)h8)[k] = 0;
        __syncthreads();
        for (int i = t; i < NA; i += 1024) {
            float sk = skey[(size_t)b * NA + i];
            unsigned u = __float_as_uint(sk);
            u = (u & 0x80000000u) ? ~u : (u | 0x80000000u);
            int b1 = (int)(u >> 20), b2 = (int)((u >> 8) & 0xFFFu);
            int digit; bool pred;
            if (level == 0)      { digit = b1;                pred = true; }
            else if (level == 1) { digit = b2;                pred = (b1 == cuts[0]); }
            else                 { digit = (36863 - i) >> 4;  pred = (b1 == cuts[0] && b2 == cuts[1]); }
            if (pred) atomicAdd(&h8[w8][digit], 1);
        }
        __syncthreads();
        for (int k = t; k < 4096; k += 1024) {
            int s = h8[0][k];
#pragma unroll
            for (int r = 1; r < 8; ++r) s += h8[r][k];
            h8[0][k] = s;
        }
        __syncthreads();
        if (t < 256) {
            int s = 0;
#pragma unroll
            for (int j = 0; j < 16; ++j) s += h8[0][t * 16 + j];
            tsum[t] = s;
        }
        __syncthreads();
        if (t == 0) {
            int run = 0;
            for (int tt = 255; tt >= 0; --tt) { int tmp = tsum[tt]; tsum[tt] = run; run += tmp; }
        }
        __syncthreads();
        if (t < 256) {
            const int target = NIN_ - cum;
            int run = tsum[t];
            for (int v = t * 16 + 15; v >= t * 16; --v) {
                int prev = run;
                run += h8[0][v];
                if (run >= target && prev < target) { s_cut = v; s_prev = prev; }
            }
        }
        __syncthreads();
        cuts[level] = s_cut;
        cum += s_prev;
        __syncthreads();
    }
    // fused compaction
    if (t == 0) lcnt = 0;
    __syncthreads();
    const int c1 = cuts[0], c2 = cuts[1], c3 = cuts[2];
    for (int i = t; i < NA; i += 1024) {
        float sk = skey[(size_t)b * NA + i];
        unsigned u = __float_as_uint(sk);
        u = (u & 0x80000000u) ? ~u : (u | 0x80000000u);
        int b1 = (int)(u >> 20), b2 = (int)((u >> 8) & 0xFFFu), b3 = (36863 - i) >> 4;
        bool take = (b1 > c1) || (b1 == c1 && (b2 > c2 || (b2 == c2 && b3 >= c3)));
        if (take) {
            int pos = atomicAdd(&lcnt, 1);
            ckey[(size_t)b * NA + pos] =
                ((unsigned long long)u << 16) | (unsigned long long)(36863 - i);
        }
    }
    __syncthreads();
    if (t == 0) cnt[b] = lcnt;
}

// ---------------- K4d: counting-rank over compacted keys (C<6016), emit top-6000 ------
// grid (24, 4): thread <-> candidate; rank = #{keys > mine} (keys unique) -> exact
// sort position; ranks 0..5999 each hit exactly once. Replaces the 4-block bitonic.
__global__ __launch_bounds__(256) void k4d_rank(const int* __restrict__ cnt,
                                                const unsigned long long* __restrict__ ckey,
                                                const float* __restrict__ rois4,
                                                float* __restrict__ rois_s,
                                                int* __restrict__ valid_s) {
    const int b = blockIdx.y;
    const int C = cnt[b];
    if (blockIdx.x * 256 >= C) return;
    const int gi = blockIdx.x * 256 + threadIdx.x;
    const bool act = gi < C;
    const unsigned long long mk = act ? ckey[(size_t)b * NA + gi] : 0ULL;
    __shared__ unsigned long long kl[512];
    int rank = 0;
    for (int c0 = 0; c0 < C; c0 += 512) {
        __syncthreads();
#pragma unroll
        for (int kk = 0; kk < 2; ++kk) {
            int k = threadIdx.x + kk * 256;
            int src = c0 + k;
            kl[k] = (src < C) ? ckey[(size_t)b * NA + src] : 0ULL;
        }
        __syncthreads();
        if (act) {
            int n = min(512, C - c0);
            int j = 0;
            for (; j + 4 <= n; j += 4) {
                rank += (kl[j]     > mk);
                rank += (kl[j + 1] > mk);
                rank += (kl[j + 2] > mk);
                rank += (kl[j + 3] > mk);
            }
            for (; j < n; ++j) rank += (kl[j] > mk);
        }
    }
    if (act && rank < NIN_) {
        int p = 36863 - (int)(mk & 0xFFFFull);
        const float4 bx = *(const float4*)&rois4[((size_t)b * NA + p) * 4];
        *(float4*)&rois_s[((size_t)b * NIN_ + rank) * 4] = bx;
        valid_s[b * NIN_ + rank] = ((unsigned)(mk >> 16) != 0x007FFFFFu) ? 1 : 0;
    }
}

// ---------------- K5a: pairwise suppression bitmask matrix ----------------
__global__ __launch_bounds__(256) void k5_mat(const float* __restrict__ rois_s,
                                              unsigned long long* __restrict__ mat) {
    const int b = blockIdx.y, rb = blockIdx.x;
    const int t = threadIdx.x, wave = t >> 6, lane = t & 63;
    const int i = rb * 64 + lane;
    const bool rowok = (i < NIN_);
    __shared__ float cs[4][5][64];
    const float* bb = rois_s + (size_t)b * NIN_ * 4;

    float r0 = 0, r1 = 0, r2 = 0, r3 = 0, ra = 0;
    if (rowok) {
        float4 v = *(const float4*)&bb[(size_t)i * 4];
        r0 = v.x; r1 = v.y; r2 = v.z; r3 = v.w;
        ra = (v.z - v.x) * (v.w - v.y);
    }
    unsigned long long* mrow = mat + ((size_t)b * NIN_ + (size_t)(rowok ? i : 0)) * NW;

    if (rowok)
        for (int cb = wave; cb < rb; cb += 4) mrow[cb] = 0ull;

    for (int cb = rb + wave; cb < NW; cb += 4) {
        const int j0 = cb * 64;
        const int j  = j0 + lane;
        float4 v;
        if (j < NIN_) v = *(const float4*)&bb[(size_t)j * 4];
        else { v.x = 0; v.y = 0; v.z = 0; v.w = 0; }
        cs[wave][0][lane] = v.x; cs[wave][1][lane] = v.y;
        cs[wave][2][lane] = v.z; cs[wave][3][lane] = v.w;
        cs[wave][4][lane] = (v.z - v.x) * (v.w - v.y);
        unsigned long long wm = 0;
        if (rowok) {
#pragma unroll 8
            for (int k = 0; k < 64; ++k) {
                float yy1 = fmaxf(r0, cs[wave][0][k]), xx1 = fmaxf(r1, cs[wave][1][k]);
                float yy2 = fminf(r2, cs[wave][2][k]), xx2 = fminf(r3, cs[wave][3][k]);
                float inter = fmaxf(yy2 - yy1, 0.f) * fmaxf(xx2 - xx1, 0.f);
                float iou = inter / (ra + cs[wave][4][k] - inter + 1e-9f);
                int jj = j0 + k;
                if ((iou > 0.7f) && (jj > i) && (jj < NIN_)) wm |= (1ull << k);
            }
            mrow[cb] = wm;
        }
    }
}

// ---------------- K5b: serial greedy scan over bitmask ----------------
__global__ __launch_bounds__(64) void k5_scan(const unsigned long long* __restrict__ mat,
                                              const float* __restrict__ rois_s,
                                              const int* __restrict__ valid_s,
                                              float* __restrict__ out) {
    const int b = blockIdx.x, t = threadIdx.x;
    for (int k = t; k < NOUT2 * 4; k += 64) out[O_ROI + (size_t)b * NOUT2 * 4 + k] = 0.f;
    for (int k = t; k < NOUT2; k += 64) out[O_IDX + (size_t)b * NOUT2 + k] = (float)b;

    unsigned long long A = 0, B = 0;
    for (int w = 0; w < NW; ++w) {
        int i = w * 64 + t;
        int v = (i < NIN_) ? valid_s[b * NIN_ + i] : 0;
        unsigned long long m = __ballot(v == 0);
        if (w < 64) { if (t == w) A = m; }
        else        { if (t == w - 64) B = m; }
    }

    const unsigned long long* mb = mat + (size_t)b * NIN_ * NW;
    const float* bb = rois_s + (size_t)b * NIN_ * 4;
    int kept = 0;
    for (int w = 0; w < NW && kept < NOUT2; ++w) {
        unsigned long long cur = (w < 64) ? __shfl(A, w) : __shfl(B, w - 64);
        unsigned long long avail = ~cur;
        while (avail != 0ull && kept < NOUT2) {
            int bit = __builtin_ctzll(avail);
            int i = w * 64 + bit;
            if (t == 0) {
                float4 bx = *(const float4*)&bb[(size_t)i * 4];
                *(float4*)&out[O_ROI + ((size_t)b * NOUT2 + kept) * 4] = bx;
            }
            kept++;
            if (kept >= NOUT2) break;
            const unsigned long long* row = mb + (size_t)i * NW;
            unsigned long long rA = row[t];
            unsigned long long rB = (t < NW - 64) ? row[64 + t] : 0ull;
            A |= rA; B |= rB;
            unsigned long long rw = (w < 64) ? __shfl(rA, w) : __shfl(rB, w - 64);
            avail &= ~rw;
            avail &= ~(1ull << bit);
        }
    }
}

// ---------------- launch ----------------
extern "C" void kernel_launch(void* const* d_in, const int* in_sizes, int n_in,
                              void* d_out, int out_size, void* d_ws, size_t ws_size,
                              hipStream_t stream) {
    const float* x       = (const float*)d_in[0];
    const float* conv_w  = (const float*)d_in[1];
    const float* conv_b  = (const float*)d_in[2];
    const float* score_w = (const float*)d_in[3];
    const float* score_b = (const float*)d_in[4];
    const float* loc_w   = (const float*)d_in[5];
    const float* loc_b   = (const float*)d_in[6];
    float* out = (float*)d_out;
    float* ws  = (float*)d_ws;

    f16* whi = (f16*)(ws + W_WHI);
    f16* wlo = (f16*)(ws + W_WLO);
    f16* xsp = (f16*)(ws + W_XSP);
    const bool ps = (ws_size >= (size_t)W_END_PS * 4);   // call-invariant -> graph-safe

    k0w<<<2359296 / 256, 256, 0, stream>>>(conv_w, whi, wlo);
    if (ps) {
        k0x<<<dim3(16, 16, 4), 256, 0, stream>>>(x, xsp);
        k1_mfma<true><<<dim3(32, 4, 4), 256, 0, stream>>>(x, xsp, whi, wlo, conv_b, ws + W_H);
    } else {
        k1_mfma<false><<<dim3(32, 4, 4), 256, 0, stream>>>(x, nullptr, whi, wlo, conv_b, ws + W_H);
    }
    k2_conv1<<<dim3(64, 4), 256, 0, stream>>>(ws + W_H, score_w, score_b, loc_w, loc_b, out);
    k3_prop<<<dim3(144, 4), 256, 0, stream>>>(out, ws + W_R4, ws + W_SK);
    k4rc<<<BATCH, 1024, 0, stream>>>(ws + W_SK, (int*)(ws + W_CNT),
                                     (unsigned long long*)(ws + W_CKEY));
    k4d_rank<<<dim3(24, BATCH), 256, 0, stream>>>((const int*)(ws + W_CNT),
                                                  (const unsigned long long*)(ws + W_CKEY),
                                                  ws + W_R4, ws + W_RS, (int*)(ws + W_VS));
    k5_mat<<<dim3(NW, BATCH), 256, 0, stream>>>(ws + W_RS, (unsigned long long*)(ws + W_MAT));
    k5_scan<<<BATCH, 64, 0, stream>>>((const unsigned long long*)(ws + W_MAT),
                                      ws + W_RS, (const int*)(ws + W_VS), out);
}